// Round 1
// baseline (1182.982 us; speedup 1.0000x reference)
//
#include <hip/hip_runtime.h>
#include <hip/hip_bf16.h>
#include <stdint.h>

// SelfAttentionBlock: B=4,S=4096,C=2048,O=2048,H=8,DH=256
// Inputs/outputs fp32; internal bf16 MFMA (m97-structure GEMMs w/ global_load_lds).
//
// R1 changes vs baseline:
//   - QKV fused into ONE gemm (N=6144): A fetched once, 1 dispatch.
//   - XCD-aware chunked blockIdx swizzle in both GEMMs (T1): each XCD owns a
//     contiguous M-chunk -> A panels fetched once from HBM, B panels via L3.
//   - qkv lives fused [16384][6144]; attn overwrites q-slice; Wo GEMM lda=6144.
//
// Pipeline (path X, ws >= 288MB):
//   0) x (fp32) -> xbf (bf16)
//   1) transpose+convert Wq|Wk|Wv -> WqkvT bf16 [6144][2048]; Wo -> WoT
//   2) qkv = xbf @ Wqkv + b      (gemm_bt<N=6144>, one dispatch)
//   3) per-position 8-head attention in fused buffer (attended -> q-slice)
//   4) y = attended @ Wo + bo + x -> d_out (fp32)   (gemm_bt<N=2048>, lda=6144)
//   5) LayerNorm in place on d_out
// Path Y (ws < 288MB): QKV GEMM uses gemm_f32a (fp32 A staged raw); rest same.
//
// ws (path X): WqkvT 0..24MB | WoT 24..32 | xbf 32..96 | qkv 96..288  (=288MB)
// ws (path Y): WqkvT 0..24MB | WoT 24..32 | qkv 32..224               (=224MB)

using short8  = __attribute__((ext_vector_type(8))) short;
using floatx4 = __attribute__((ext_vector_type(4))) float;

__device__ __forceinline__ float bf2f(ushort u) {
    union { uint32_t i; float f; } v; v.i = ((uint32_t)u) << 16; return v.f;
}
__device__ __forceinline__ ushort f2bf(float f) {
    union { float f; uint32_t i; } v; v.f = f;
    uint32_t r = v.i + 0x7fffu + ((v.i >> 16) & 1u);
    return (ushort)(r >> 16);
}
__device__ __forceinline__ short8 pack8(const floatx4& a, const floatx4& b) {
    short8 o;
    o[0] = (short)f2bf(a[0]); o[1] = (short)f2bf(a[1]);
    o[2] = (short)f2bf(a[2]); o[3] = (short)f2bf(a[3]);
    o[4] = (short)f2bf(b[0]); o[5] = (short)f2bf(b[1]);
    o[6] = (short)f2bf(b[2]); o[7] = (short)f2bf(b[3]);
    return o;
}
__device__ __forceinline__ void async_copy16(const void* g, void* l) {
    __builtin_amdgcn_global_load_lds(
        (__attribute__((address_space(1))) uint32_t*)g,
        (__attribute__((address_space(3))) uint32_t*)l,
        16, 0, 0);
}

// -------- fp32 -> bf16 bulk convert (8 elems/thread) ------------------------
__global__ void cvt_bf16(const float* __restrict__ in, ushort* __restrict__ out) {
    const size_t base = ((size_t)blockIdx.x * 256 + threadIdx.x) * 8;
    floatx4 a = *(const floatx4*)&in[base];
    floatx4 b = *(const floatx4*)&in[base + 4];
    *(short8*)&out[base] = pack8(a, b);
}

// -------- weight transpose+convert: fp32 [2048][2048] -> bf16 T -------------
__global__ void convT2048(const float* __restrict__ in, ushort* __restrict__ out) {
    __shared__ alignas(16) float tile[32][33];
    const int x = blockIdx.x * 32 + threadIdx.x;
    const int y0 = blockIdx.y * 32;
    for (int j = threadIdx.y; j < 32; j += 8)
        tile[j][threadIdx.x] = in[(size_t)(y0 + j) * 2048 + x];
    __syncthreads();
    const int x2 = blockIdx.y * 32 + threadIdx.x;
    const int y2 = blockIdx.x * 32;
    for (int j = threadIdx.y; j < 32; j += 8)
        out[(size_t)(y2 + j) * 2048 + x2] = f2bf(tile[threadIdx.x][j]);
}

// -------- m97 GEMM: C[M][N] = A_bf16[M][2048](lda) @ Bt^T + bias (+resid) ---
// 128x128 tile, BK=32, 4 waves x (4x4) 16x16x32 MFMA, global_load_lds w=16.
// 1D grid of N/128 * M/128 blocks (must be divisible by 8); XCD-chunk swizzle.
// Bias selected per column block from {b0,b1,b2} (fused QKV support).
template <typename CT, int N>
__global__ __launch_bounds__(256, 2)
void gemm_bt(const ushort* __restrict__ A, int lda,
             const ushort* __restrict__ Bt,
             const float* __restrict__ b0, const float* __restrict__ b1,
             const float* __restrict__ b2,
             const float* __restrict__ resid, CT* __restrict__ C)
{
    constexpr int K = 2048;
    constexpr int NT = N / 128;
    __shared__ alignas(16) ushort lA[128 * 32];
    __shared__ alignas(16) ushort lB[128 * 32];

    const int t = threadIdx.x;
    const int wave = t >> 6, lane = t & 63;

    // T1: XCD-aware chunked swizzle. HW round-robins dispatch id l over 8 XCDs;
    // remap so each XCD gets a contiguous chunk of the (M-major) logical grid.
    const int nwg = (int)gridDim.x;         // divisible by 8
    const int chunk = nwg >> 3;
    const int l = (int)blockIdx.x;
    const int logical = (l & 7) * chunk + (l >> 3);
    const int row0 = (logical / NT) * 128;
    const int col0 = (logical % NT) * 128;

    // bias select is block-uniform (tiles never straddle a 2048 boundary)
    const float* bias; int boff;
    if (col0 < 2048)      { bias = b0; boff = 0; }
    else if (col0 < 4096) { bias = b1; boff = 2048; }
    else                  { bias = b2; boff = 4096; }

    // staging: thread t owns 16B -> tile row t/4, cols (t%4)*8..+7
    // LDS linear t*8 = wave-uniform base (wave*512) + lane*8  (DMA-compatible)
    const int sr = t >> 2, sc = (t & 3) * 8;
    const ushort* gA0 = A + (size_t)(row0 + sr) * lda + sc;
    const ushort* gA1 = A + (size_t)(row0 + 64 + sr) * lda + sc;
    const ushort* gB0 = Bt + (size_t)(col0 + sr) * K + sc;
    const ushort* gB1 = Bt + (size_t)(col0 + 64 + sr) * K + sc;
    ushort* lA0 = &lA[t * 8];
    ushort* lA1 = &lA[2048 + t * 8];
    ushort* lB0 = &lB[t * 8];
    ushort* lB1 = &lB[2048 + t * 8];

    const int wm = (wave >> 1) * 64;
    const int wn = (wave & 1) * 64;
    const int q4 = lane >> 4;
    const int lr = lane & 15;

    floatx4 acc[4][4];
    #pragma unroll
    for (int i = 0; i < 4; i++)
        #pragma unroll
        for (int j = 0; j < 4; j++)
            acc[i][j] = (floatx4){0.f, 0.f, 0.f, 0.f};

    for (int kt = 0; kt < K / 32; ++kt) {
        const int ko = kt * 32;
        async_copy16(gA0 + ko, lA0);
        async_copy16(gA1 + ko, lA1);
        async_copy16(gB0 + ko, lB0);
        async_copy16(gB1 + ko, lB1);
        __syncthreads();   // drains vmcnt(0): DMA landed, all waves' prior reads done

        short8 af[4], bfr[4];
        #pragma unroll
        for (int i = 0; i < 4; i++)
            af[i] = *(const short8*)&lA[(wm + i * 16 + lr) * 32 + q4 * 8];
        #pragma unroll
        for (int j = 0; j < 4; j++)
            bfr[j] = *(const short8*)&lB[(wn + j * 16 + lr) * 32 + q4 * 8];

        #pragma unroll
        for (int i = 0; i < 4; i++)
            #pragma unroll
            for (int j = 0; j < 4; j++)
                acc[i][j] = __builtin_amdgcn_mfma_f32_16x16x32_bf16(
                    af[i], bfr[j], acc[i][j], 0, 0, 0);
        __syncthreads();   // all reads retired before next iter's DMA overwrites
    }

    // epilogue: D[row=quad*4+reg][col=lane&15]
    #pragma unroll
    for (int j = 0; j < 4; j++) {
        const int gcol = col0 + wn + j * 16 + lr;
        const float bv = bias[gcol - boff];
        #pragma unroll
        for (int i = 0; i < 4; i++) {
            #pragma unroll
            for (int r = 0; r < 4; r++) {
                const int grow = row0 + wm + i * 16 + q4 * 4 + r;
                const size_t off = (size_t)grow * N + gcol;
                float v = acc[i][j][r] + bv;
                if (resid) v += resid[off];
                if constexpr (__is_same(CT, float)) C[off] = v;
                else                                C[off] = f2bf(v);
            }
        }
    }
}

// -------- fallback GEMM: fp32 A staged raw via global_load_lds, cvt in regs -
template <int N>
__global__ __launch_bounds__(256, 2)
void gemm_f32a(const float* __restrict__ A, int lda,
               const ushort* __restrict__ Bt,
               const float* __restrict__ b0, const float* __restrict__ b1,
               const float* __restrict__ b2, ushort* __restrict__ C)
{
    constexpr int K = 2048;
    constexpr int NT = N / 128;
    __shared__ alignas(16) float  lA32[128 * 32];   // 16KB
    __shared__ alignas(16) ushort lB[128 * 32];     // 8KB

    const int t = threadIdx.x;
    const int wave = t >> 6, lane = t & 63;

    const int nwg = (int)gridDim.x;
    const int chunk = nwg >> 3;
    const int l = (int)blockIdx.x;
    const int logical = (l & 7) * chunk + (l >> 3);
    const int row0 = (logical / NT) * 128;
    const int col0 = (logical % NT) * 128;

    const float* bias; int boff;
    if (col0 < 2048)      { bias = b0; boff = 0; }
    else if (col0 < 4096) { bias = b1; boff = 2048; }
    else                  { bias = b2; boff = 4096; }

    // A staging: chunk c = n*256+t -> row c/8, cols (c%8)*4..+3 (fp32, 16B)
    const int ar = t >> 3, ac = (t & 7) * 4;
    const float* gA0 = A + (size_t)(row0 + ar) * lda + ac;
    const ushort* gB0 = Bt + (size_t)(col0 + (t >> 2)) * K + (t & 3) * 8;
    const ushort* gB1 = Bt + (size_t)(col0 + 64 + (t >> 2)) * K + (t & 3) * 8;

    const int wm = (wave >> 1) * 64;
    const int wn = (wave & 1) * 64;
    const int q4 = lane >> 4;
    const int lr = lane & 15;

    floatx4 acc[4][4];
    #pragma unroll
    for (int i = 0; i < 4; i++)
        #pragma unroll
        for (int j = 0; j < 4; j++)
            acc[i][j] = (floatx4){0.f, 0.f, 0.f, 0.f};

    for (int kt = 0; kt < K / 32; ++kt) {
        const int ko = kt * 32;
        #pragma unroll
        for (int n = 0; n < 4; n++)
            async_copy16(gA0 + (size_t)n * 32 * lda + ko, &lA32[(n * 256 + t) * 4]);
        async_copy16(gB0 + ko, &lB[t * 8]);
        async_copy16(gB1 + ko, &lB[2048 + t * 8]);
        __syncthreads();

        short8 af[4], bfr[4];
        #pragma unroll
        for (int i = 0; i < 4; i++) {
            const floatx4* pa = (const floatx4*)&lA32[(wm + i * 16 + lr) * 32 + q4 * 8];
            af[i] = pack8(pa[0], pa[1]);
        }
        #pragma unroll
        for (int j = 0; j < 4; j++)
            bfr[j] = *(const short8*)&lB[(wn + j * 16 + lr) * 32 + q4 * 8];

        #pragma unroll
        for (int i = 0; i < 4; i++)
            #pragma unroll
            for (int j = 0; j < 4; j++)
                acc[i][j] = __builtin_amdgcn_mfma_f32_16x16x32_bf16(
                    af[i], bfr[j], acc[i][j], 0, 0, 0);
        __syncthreads();
    }

    #pragma unroll
    for (int j = 0; j < 4; j++) {
        const int gcol = col0 + wn + j * 16 + lr;
        const float bv = bias[gcol - boff];
        #pragma unroll
        for (int i = 0; i < 4; i++)
            #pragma unroll
            for (int r = 0; r < 4; r++) {
                const int grow = row0 + wm + i * 16 + q4 * 4 + r;
                C[(size_t)grow * N + gcol] = f2bf(acc[i][j][r] + bv);
            }
    }
}

// -------- per-position attention on fused qkv [16384][6144], bf16 ----------
// one wave per (b,s); reads q/k/v slices, writes attended into q-slice.
__global__ __launch_bounds__(256, 2)
void attn_kernel(ushort* __restrict__ qkv)
{
    __shared__ alignas(16) ushort sq[4][2048];
    __shared__ alignas(16) ushort sk[4][2048];
    __shared__ alignas(16) ushort sv[4][2048];
    const int wave = threadIdx.x >> 6, lane = threadIdx.x & 63;
    const size_t p = (size_t)blockIdx.x * 4 + wave;
    const size_t base = p * 6144;

    #pragma unroll
    for (int c = 0; c < 4; c++) {
        const int idx = c * 512 + lane * 8;
        *(short8*)&sq[wave][idx] = *(const short8*)&qkv[base + idx];
        *(short8*)&sk[wave][idx] = *(const short8*)&qkv[base + 2048 + idx];
        *(short8*)&sv[wave][idx] = *(const short8*)&qkv[base + 4096 + idx];
    }

    const int h = lane >> 3;
    const int tt = lane & 7;
    float s = 0.f;
    #pragma unroll 4
    for (int c = 0; c < 32; c++) {
        short8 qv = *(const short8*)&sq[wave][h * 256 + c * 8];
        short8 kv = *(const short8*)&sk[wave][tt * 256 + c * 8];
        #pragma unroll
        for (int e = 0; e < 8; e++)
            s += bf2f((ushort)qv[e]) * bf2f((ushort)kv[e]);
    }
    s *= (1.0f / 16.0f);   // 1/sqrt(256)

    float m = s;
    m = fmaxf(m, __shfl_xor(m, 1));
    m = fmaxf(m, __shfl_xor(m, 2));
    m = fmaxf(m, __shfl_xor(m, 4));
    float e = __expf(s - m);
    float sum = e;
    sum += __shfl_xor(sum, 1);
    sum += __shfl_xor(sum, 2);
    sum += __shfl_xor(sum, 4);
    const float w = e / sum;

    float wt[8];
    #pragma unroll
    for (int t2 = 0; t2 < 8; t2++)
        wt[t2] = __shfl(w, (lane & 56) + t2);

    const int d0 = (lane & 7) * 8;
    #pragma unroll
    for (int c = 0; c < 4; c++) {
        const int d = d0 + c * 64;
        float acc[8] = {0, 0, 0, 0, 0, 0, 0, 0};
        #pragma unroll
        for (int t2 = 0; t2 < 8; t2++) {
            short8 vv = *(const short8*)&sv[wave][t2 * 256 + d];
            #pragma unroll
            for (int e2 = 0; e2 < 8; e2++)
                acc[e2] += wt[t2] * bf2f((ushort)vv[e2]);
        }
        short8 o;
        #pragma unroll
        for (int e2 = 0; e2 < 8; e2++)
            o[e2] = (short)f2bf(acc[e2]);
        *(short8*)&qkv[base + h * 256 + d] = o;
    }
}

// -------- LayerNorm over C=2048, fp32 in place on d_out ---------------------
__global__ __launch_bounds__(256, 2)
void ln_kernel(float* __restrict__ y, const float* __restrict__ gamma,
               const float* __restrict__ beta)
{
    __shared__ float red[2][4];
    const int t = threadIdx.x;
    const size_t base = (size_t)blockIdx.x * 2048 + t * 8;
    floatx4 a = *(const floatx4*)&y[base];
    floatx4 b = *(const floatx4*)&y[base + 4];
    float f[8] = {a[0], a[1], a[2], a[3], b[0], b[1], b[2], b[3]};
    float s = 0.f, ss = 0.f;
    #pragma unroll
    for (int e = 0; e < 8; e++) { s += f[e]; ss += f[e] * f[e]; }
    #pragma unroll
    for (int off = 1; off < 64; off <<= 1) {
        s  += __shfl_xor(s, off);
        ss += __shfl_xor(ss, off);
    }
    const int wave = t >> 6, lane = t & 63;
    if (lane == 0) { red[0][wave] = s; red[1][wave] = ss; }
    __syncthreads();
    s  = red[0][0] + red[0][1] + red[0][2] + red[0][3];
    ss = red[1][0] + red[1][1] + red[1][2] + red[1][3];
    const float mu  = s * (1.f / 2048.f);
    const float var = fmaxf(ss * (1.f / 2048.f) - mu * mu, 0.f);
    const float rs  = rsqrtf(var + 1e-5f);
    floatx4 g0 = *(const floatx4*)&gamma[t * 8];
    floatx4 g1 = *(const floatx4*)&gamma[t * 8 + 4];
    floatx4 b0 = *(const floatx4*)&beta[t * 8];
    floatx4 b1 = *(const floatx4*)&beta[t * 8 + 4];
    floatx4 o0, o1;
    #pragma unroll
    for (int e = 0; e < 4; e++) {
        o0[e] = g0[e] * (f[e] - mu) * rs + b0[e];
        o1[e] = g1[e] * (f[e + 4] - mu) * rs + b1[e];
    }
    *(floatx4*)&y[base]     = o0;
    *(floatx4*)&y[base + 4] = o1;
}

extern "C" void kernel_launch(void* const* d_in, const int* in_sizes, int n_in,
                              void* d_out, int out_size, void* d_ws, size_t ws_size,
                              hipStream_t stream)
{
    const float* x     = (const float*)d_in[0];
    const float* Wq    = (const float*)d_in[1];
    const float* bq    = (const float*)d_in[2];
    const float* Wk    = (const float*)d_in[3];
    const float* bk    = (const float*)d_in[4];
    const float* Wv    = (const float*)d_in[5];
    const float* bv    = (const float*)d_in[6];
    const float* Wo    = (const float*)d_in[7];
    const float* bo    = (const float*)d_in[8];
    const float* gamma = (const float*)d_in[9];
    const float* beta  = (const float*)d_in[10];
    float* out = (float*)d_out;

    char* ws = (char*)d_ws;
    const size_t MB = 1024 * 1024;
    ushort* WqkvT = (ushort*)(ws + 0 * MB);    // 24MB: Wq^T | Wk^T | Wv^T rows
    ushort* WoT   = (ushort*)(ws + 24 * MB);   // 8MB

    const bool bigws = ws_size >= 288 * MB;
    ushort* xbf = (ushort*)(ws + 32 * MB);                      // path X: 64MB
    ushort* qkv = (ushort*)(ws + (bigws ? 96 : 32) * MB);       // 192MB fused

    dim3 tb(32, 8), tg(64, 64);
    convT2048<<<tg, tb, 0, stream>>>(Wq, WqkvT);
    convT2048<<<tg, tb, 0, stream>>>(Wk, WqkvT + 2048 * 2048);
    convT2048<<<tg, tb, 0, stream>>>(Wv, WqkvT + 2 * 2048 * 2048);
    convT2048<<<tg, tb, 0, stream>>>(Wo, WoT);

    if (bigws) {
        cvt_bf16<<<16384, 256, 0, stream>>>(x, xbf);
        // fused QKV: [16384][2048] @ [6144][2048]^T -> [16384][6144]
        gemm_bt<ushort, 6144><<<6144, 256, 0, stream>>>(
            xbf, 2048, WqkvT, bq, bk, bv, nullptr, qkv);
    } else {
        gemm_f32a<6144><<<6144, 256, 0, stream>>>(
            x, 2048, WqkvT, bq, bk, bv, qkv);
    }

    attn_kernel<<<4096, 256, 0, stream>>>(qkv);

    // attended lives in q-slice of fused buffer (lda=6144)
    gemm_bt<float, 2048><<<2048, 256, 0, stream>>>(
        qkv, 6144, WoT, bo, bo, bo, x, out);

    ln_kernel<<<16384, 256, 0, stream>>>(out, gamma, beta);
}

// Round 2
// 1118.452 us; speedup vs baseline: 1.0577x; 1.0577x over previous
//
#include <hip/hip_runtime.h>
#include <hip/hip_bf16.h>
#include <stdint.h>

// SelfAttentionBlock: B=4,S=4096,C=2048,O=2048,H=8,DH=256
// Inputs/outputs fp32; internal bf16 MFMA (m97-structure GEMMs w/ global_load_lds).
//
// R2 changes vs R1:
//   - FIXED XCD mapping: R1 gave each XCD an M-chunk traversed N-fastest ->
//     B-panels re-streamed through L2 once per M-row (FETCH 1.53GB, +35us).
//     Now each XCD owns a contiguous N-STRIPE (NT/8 B-panels, L2-resident:
//     QKV 3MB, Wo 1MB) and iterates M-major. A streams once per XCD via L3.
//     decode: xcd=l%8, j=l/8, m=j/SW, c=j%SW, col0=(xcd*SW+c)*128.
//
// Pipeline (path X, ws >= 288MB):
//   0) x (fp32) -> xbf (bf16)
//   1) transpose+convert Wq|Wk|Wv -> WqkvT bf16 [6144][2048]; Wo -> WoT
//   2) qkv = xbf @ Wqkv + b      (gemm_bt<N=6144>, one dispatch)
//   3) per-position 8-head attention in fused buffer (attended -> q-slice)
//   4) y = attended @ Wo + bo + x -> d_out (fp32)   (gemm_bt<N=2048>, lda=6144)
//   5) LayerNorm in place on d_out
// Path Y (ws < 288MB): QKV GEMM uses gemm_f32a (fp32 A staged raw); rest same.
//
// ws (path X): WqkvT 0..24MB | WoT 24..32 | xbf 32..96 | qkv 96..288  (=288MB)
// ws (path Y): WqkvT 0..24MB | WoT 24..32 | qkv 32..224               (=224MB)

using short8  = __attribute__((ext_vector_type(8))) short;
using floatx4 = __attribute__((ext_vector_type(4))) float;

__device__ __forceinline__ float bf2f(ushort u) {
    union { uint32_t i; float f; } v; v.i = ((uint32_t)u) << 16; return v.f;
}
__device__ __forceinline__ ushort f2bf(float f) {
    union { float f; uint32_t i; } v; v.f = f;
    uint32_t r = v.i + 0x7fffu + ((v.i >> 16) & 1u);
    return (ushort)(r >> 16);
}
__device__ __forceinline__ short8 pack8(const floatx4& a, const floatx4& b) {
    short8 o;
    o[0] = (short)f2bf(a[0]); o[1] = (short)f2bf(a[1]);
    o[2] = (short)f2bf(a[2]); o[3] = (short)f2bf(a[3]);
    o[4] = (short)f2bf(b[0]); o[5] = (short)f2bf(b[1]);
    o[6] = (short)f2bf(b[2]); o[7] = (short)f2bf(b[3]);
    return o;
}
__device__ __forceinline__ void async_copy16(const void* g, void* l) {
    __builtin_amdgcn_global_load_lds(
        (__attribute__((address_space(1))) uint32_t*)g,
        (__attribute__((address_space(3))) uint32_t*)l,
        16, 0, 0);
}

// -------- fp32 -> bf16 bulk convert (8 elems/thread) ------------------------
__global__ void cvt_bf16(const float* __restrict__ in, ushort* __restrict__ out) {
    const size_t base = ((size_t)blockIdx.x * 256 + threadIdx.x) * 8;
    floatx4 a = *(const floatx4*)&in[base];
    floatx4 b = *(const floatx4*)&in[base + 4];
    *(short8*)&out[base] = pack8(a, b);
}

// -------- weight transpose+convert: fp32 [2048][2048] -> bf16 T -------------
__global__ void convT2048(const float* __restrict__ in, ushort* __restrict__ out) {
    __shared__ alignas(16) float tile[32][33];
    const int x = blockIdx.x * 32 + threadIdx.x;
    const int y0 = blockIdx.y * 32;
    for (int j = threadIdx.y; j < 32; j += 8)
        tile[j][threadIdx.x] = in[(size_t)(y0 + j) * 2048 + x];
    __syncthreads();
    const int x2 = blockIdx.y * 32 + threadIdx.x;
    const int y2 = blockIdx.x * 32;
    for (int j = threadIdx.y; j < 32; j += 8)
        out[(size_t)(y2 + j) * 2048 + x2] = f2bf(tile[threadIdx.x][j]);
}

// -------- m97 GEMM: C[M][N] = A_bf16[M][2048](lda) @ Bt^T + bias (+resid) ---
// 128x128 tile, BK=32, 4 waves x (4x4) 16x16x32 MFMA, global_load_lds w=16.
// 1D grid of (M/128)*(N/128) blocks. XCD N-stripe mapping (see header).
// Bias selected per column block from {b0,b1,b2} (fused QKV support).
template <typename CT, int N>
__global__ __launch_bounds__(256, 2)
void gemm_bt(const ushort* __restrict__ A, int lda,
             const ushort* __restrict__ Bt,
             const float* __restrict__ b0, const float* __restrict__ b1,
             const float* __restrict__ b2,
             const float* __restrict__ resid, CT* __restrict__ C)
{
    constexpr int K = 2048;
    constexpr int NT = N / 128;     // N-tiles
    constexpr int SW = NT / 8;      // stripe width per XCD (B L2-resident)
    __shared__ alignas(16) ushort lA[128 * 32];
    __shared__ alignas(16) ushort lB[128 * 32];

    const int t = threadIdx.x;
    const int wave = t >> 6, lane = t & 63;

    // XCD N-stripe decode: HW round-robins hardware id l over 8 XCDs.
    const int l = (int)blockIdx.x;
    const int xcd = l & 7;
    const int j2 = l >> 3;          // per-XCD sequence, M-major within stripe
    const int row0 = (j2 / SW) * 128;
    const int col0 = (xcd * SW + (j2 % SW)) * 128;

    // bias select is block-uniform (tiles never straddle a 2048 boundary)
    const float* bias; int boff;
    if (col0 < 2048)      { bias = b0; boff = 0; }
    else if (col0 < 4096) { bias = b1; boff = 2048; }
    else                  { bias = b2; boff = 4096; }

    // staging: thread t owns 16B -> tile row t/4, cols (t%4)*8..+7
    // LDS linear t*8 = wave-uniform base (wave*512) + lane*8  (DMA-compatible)
    const int sr = t >> 2, sc = (t & 3) * 8;
    const ushort* gA0 = A + (size_t)(row0 + sr) * lda + sc;
    const ushort* gA1 = A + (size_t)(row0 + 64 + sr) * lda + sc;
    const ushort* gB0 = Bt + (size_t)(col0 + sr) * K + sc;
    const ushort* gB1 = Bt + (size_t)(col0 + 64 + sr) * K + sc;
    ushort* lA0 = &lA[t * 8];
    ushort* lA1 = &lA[2048 + t * 8];
    ushort* lB0 = &lB[t * 8];
    ushort* lB1 = &lB[2048 + t * 8];

    const int wm = (wave >> 1) * 64;
    const int wn = (wave & 1) * 64;
    const int q4 = lane >> 4;
    const int lr = lane & 15;

    floatx4 acc[4][4];
    #pragma unroll
    for (int i = 0; i < 4; i++)
        #pragma unroll
        for (int j = 0; j < 4; j++)
            acc[i][j] = (floatx4){0.f, 0.f, 0.f, 0.f};

    for (int kt = 0; kt < K / 32; ++kt) {
        const int ko = kt * 32;
        async_copy16(gA0 + ko, lA0);
        async_copy16(gA1 + ko, lA1);
        async_copy16(gB0 + ko, lB0);
        async_copy16(gB1 + ko, lB1);
        __syncthreads();   // drains vmcnt(0): DMA landed, all waves' prior reads done

        short8 af[4], bfr[4];
        #pragma unroll
        for (int i = 0; i < 4; i++)
            af[i] = *(const short8*)&lA[(wm + i * 16 + lr) * 32 + q4 * 8];
        #pragma unroll
        for (int j = 0; j < 4; j++)
            bfr[j] = *(const short8*)&lB[(wn + j * 16 + lr) * 32 + q4 * 8];

        #pragma unroll
        for (int i = 0; i < 4; i++)
            #pragma unroll
            for (int j = 0; j < 4; j++)
                acc[i][j] = __builtin_amdgcn_mfma_f32_16x16x32_bf16(
                    af[i], bfr[j], acc[i][j], 0, 0, 0);
        __syncthreads();   // all reads retired before next iter's DMA overwrites
    }

    // epilogue: D[row=quad*4+reg][col=lane&15]
    #pragma unroll
    for (int j = 0; j < 4; j++) {
        const int gcol = col0 + wn + j * 16 + lr;
        const float bv = bias[gcol - boff];
        #pragma unroll
        for (int i = 0; i < 4; i++) {
            #pragma unroll
            for (int r = 0; r < 4; r++) {
                const int grow = row0 + wm + i * 16 + q4 * 4 + r;
                const size_t off = (size_t)grow * N + gcol;
                float v = acc[i][j][r] + bv;
                if (resid) v += resid[off];
                if constexpr (__is_same(CT, float)) C[off] = v;
                else                                C[off] = f2bf(v);
            }
        }
    }
}

// -------- fallback GEMM: fp32 A staged raw via global_load_lds, cvt in regs -
template <int N>
__global__ __launch_bounds__(256, 2)
void gemm_f32a(const float* __restrict__ A, int lda,
               const ushort* __restrict__ Bt,
               const float* __restrict__ b0, const float* __restrict__ b1,
               const float* __restrict__ b2, ushort* __restrict__ C)
{
    constexpr int K = 2048;
    constexpr int NT = N / 128;
    constexpr int SW = NT / 8;
    __shared__ alignas(16) float  lA32[128 * 32];   // 16KB
    __shared__ alignas(16) ushort lB[128 * 32];     // 8KB

    const int t = threadIdx.x;
    const int wave = t >> 6, lane = t & 63;

    const int l = (int)blockIdx.x;
    const int xcd = l & 7;
    const int j2 = l >> 3;
    const int row0 = (j2 / SW) * 128;
    const int col0 = (xcd * SW + (j2 % SW)) * 128;

    const float* bias; int boff;
    if (col0 < 2048)      { bias = b0; boff = 0; }
    else if (col0 < 4096) { bias = b1; boff = 2048; }
    else                  { bias = b2; boff = 4096; }

    // A staging: chunk c = n*256+t -> row c/8, cols (c%8)*4..+3 (fp32, 16B)
    const int ar = t >> 3, ac = (t & 7) * 4;
    const float* gA0 = A + (size_t)(row0 + ar) * lda + ac;
    const ushort* gB0 = Bt + (size_t)(col0 + (t >> 2)) * K + (t & 3) * 8;
    const ushort* gB1 = Bt + (size_t)(col0 + 64 + (t >> 2)) * K + (t & 3) * 8;

    const int wm = (wave >> 1) * 64;
    const int wn = (wave & 1) * 64;
    const int q4 = lane >> 4;
    const int lr = lane & 15;

    floatx4 acc[4][4];
    #pragma unroll
    for (int i = 0; i < 4; i++)
        #pragma unroll
        for (int j = 0; j < 4; j++)
            acc[i][j] = (floatx4){0.f, 0.f, 0.f, 0.f};

    for (int kt = 0; kt < K / 32; ++kt) {
        const int ko = kt * 32;
        #pragma unroll
        for (int n = 0; n < 4; n++)
            async_copy16(gA0 + (size_t)n * 32 * lda + ko, &lA32[(n * 256 + t) * 4]);
        async_copy16(gB0 + ko, &lB[t * 8]);
        async_copy16(gB1 + ko, &lB[2048 + t * 8]);
        __syncthreads();

        short8 af[4], bfr[4];
        #pragma unroll
        for (int i = 0; i < 4; i++) {
            const floatx4* pa = (const floatx4*)&lA32[(wm + i * 16 + lr) * 32 + q4 * 8];
            af[i] = pack8(pa[0], pa[1]);
        }
        #pragma unroll
        for (int j = 0; j < 4; j++)
            bfr[j] = *(const short8*)&lB[(wn + j * 16 + lr) * 32 + q4 * 8];

        #pragma unroll
        for (int i = 0; i < 4; i++)
            #pragma unroll
            for (int j = 0; j < 4; j++)
                acc[i][j] = __builtin_amdgcn_mfma_f32_16x16x32_bf16(
                    af[i], bfr[j], acc[i][j], 0, 0, 0);
        __syncthreads();
    }

    #pragma unroll
    for (int j = 0; j < 4; j++) {
        const int gcol = col0 + wn + j * 16 + lr;
        const float bv = bias[gcol - boff];
        #pragma unroll
        for (int i = 0; i < 4; i++)
            #pragma unroll
            for (int r = 0; r < 4; r++) {
                const int grow = row0 + wm + i * 16 + q4 * 4 + r;
                C[(size_t)grow * N + gcol] = f2bf(acc[i][j][r] + bv);
            }
    }
}

// -------- per-position attention on fused qkv [16384][6144], bf16 ----------
// one wave per (b,s); reads q/k/v slices, writes attended into q-slice.
__global__ __launch_bounds__(256, 2)
void attn_kernel(ushort* __restrict__ qkv)
{
    __shared__ alignas(16) ushort sq[4][2048];
    __shared__ alignas(16) ushort sk[4][2048];
    __shared__ alignas(16) ushort sv[4][2048];
    const int wave = threadIdx.x >> 6, lane = threadIdx.x & 63;
    const size_t p = (size_t)blockIdx.x * 4 + wave;
    const size_t base = p * 6144;

    #pragma unroll
    for (int c = 0; c < 4; c++) {
        const int idx = c * 512 + lane * 8;
        *(short8*)&sq[wave][idx] = *(const short8*)&qkv[base + idx];
        *(short8*)&sk[wave][idx] = *(const short8*)&qkv[base + 2048 + idx];
        *(short8*)&sv[wave][idx] = *(const short8*)&qkv[base + 4096 + idx];
    }

    const int h = lane >> 3;
    const int tt = lane & 7;
    float s = 0.f;
    #pragma unroll 4
    for (int c = 0; c < 32; c++) {
        short8 qv = *(const short8*)&sq[wave][h * 256 + c * 8];
        short8 kv = *(const short8*)&sk[wave][tt * 256 + c * 8];
        #pragma unroll
        for (int e = 0; e < 8; e++)
            s += bf2f((ushort)qv[e]) * bf2f((ushort)kv[e]);
    }
    s *= (1.0f / 16.0f);   // 1/sqrt(256)

    float m = s;
    m = fmaxf(m, __shfl_xor(m, 1));
    m = fmaxf(m, __shfl_xor(m, 2));
    m = fmaxf(m, __shfl_xor(m, 4));
    float e = __expf(s - m);
    float sum = e;
    sum += __shfl_xor(sum, 1);
    sum += __shfl_xor(sum, 2);
    sum += __shfl_xor(sum, 4);
    const float w = e / sum;

    float wt[8];
    #pragma unroll
    for (int t2 = 0; t2 < 8; t2++)
        wt[t2] = __shfl(w, (lane & 56) + t2);

    const int d0 = (lane & 7) * 8;
    #pragma unroll
    for (int c = 0; c < 4; c++) {
        const int d = d0 + c * 64;
        float acc[8] = {0, 0, 0, 0, 0, 0, 0, 0};
        #pragma unroll
        for (int t2 = 0; t2 < 8; t2++) {
            short8 vv = *(const short8*)&sv[wave][t2 * 256 + d];
            #pragma unroll
            for (int e2 = 0; e2 < 8; e2++)
                acc[e2] += wt[t2] * bf2f((ushort)vv[e2]);
        }
        short8 o;
        #pragma unroll
        for (int e2 = 0; e2 < 8; e2++)
            o[e2] = (short)f2bf(acc[e2]);
        *(short8*)&qkv[base + h * 256 + d] = o;
    }
}

// -------- LayerNorm over C=2048, fp32 in place on d_out ---------------------
__global__ __launch_bounds__(256, 2)
void ln_kernel(float* __restrict__ y, const float* __restrict__ gamma,
               const float* __restrict__ beta)
{
    __shared__ float red[2][4];
    const int t = threadIdx.x;
    const size_t base = (size_t)blockIdx.x * 2048 + t * 8;
    floatx4 a = *(const floatx4*)&y[base];
    floatx4 b = *(const floatx4*)&y[base + 4];
    float f[8] = {a[0], a[1], a[2], a[3], b[0], b[1], b[2], b[3]};
    float s = 0.f, ss = 0.f;
    #pragma unroll
    for (int e = 0; e < 8; e++) { s += f[e]; ss += f[e] * f[e]; }
    #pragma unroll
    for (int off = 1; off < 64; off <<= 1) {
        s  += __shfl_xor(s, off);
        ss += __shfl_xor(ss, off);
    }
    const int wave = t >> 6, lane = t & 63;
    if (lane == 0) { red[0][wave] = s; red[1][wave] = ss; }
    __syncthreads();
    s  = red[0][0] + red[0][1] + red[0][2] + red[0][3];
    ss = red[1][0] + red[1][1] + red[1][2] + red[1][3];
    const float mu  = s * (1.f / 2048.f);
    const float var = fmaxf(ss * (1.f / 2048.f) - mu * mu, 0.f);
    const float rs  = rsqrtf(var + 1e-5f);
    floatx4 g0 = *(const floatx4*)&gamma[t * 8];
    floatx4 g1 = *(const floatx4*)&gamma[t * 8 + 4];
    floatx4 b0 = *(const floatx4*)&beta[t * 8];
    floatx4 b1 = *(const floatx4*)&beta[t * 8 + 4];
    floatx4 o0, o1;
    #pragma unroll
    for (int e = 0; e < 4; e++) {
        o0[e] = g0[e] * (f[e] - mu) * rs + b0[e];
        o1[e] = g1[e] * (f[e + 4] - mu) * rs + b1[e];
    }
    *(floatx4*)&y[base]     = o0;
    *(floatx4*)&y[base + 4] = o1;
}

extern "C" void kernel_launch(void* const* d_in, const int* in_sizes, int n_in,
                              void* d_out, int out_size, void* d_ws, size_t ws_size,
                              hipStream_t stream)
{
    const float* x     = (const float*)d_in[0];
    const float* Wq    = (const float*)d_in[1];
    const float* bq    = (const float*)d_in[2];
    const float* Wk    = (const float*)d_in[3];
    const float* bk    = (const float*)d_in[4];
    const float* Wv    = (const float*)d_in[5];
    const float* bv    = (const float*)d_in[6];
    const float* Wo    = (const float*)d_in[7];
    const float* bo    = (const float*)d_in[8];
    const float* gamma = (const float*)d_in[9];
    const float* beta  = (const float*)d_in[10];
    float* out = (float*)d_out;

    char* ws = (char*)d_ws;
    const size_t MB = 1024 * 1024;
    ushort* WqkvT = (ushort*)(ws + 0 * MB);    // 24MB: Wq^T | Wk^T | Wv^T rows
    ushort* WoT   = (ushort*)(ws + 24 * MB);   // 8MB

    const bool bigws = ws_size >= 288 * MB;
    ushort* xbf = (ushort*)(ws + 32 * MB);                      // path X: 64MB
    ushort* qkv = (ushort*)(ws + (bigws ? 96 : 32) * MB);       // 192MB fused

    dim3 tb(32, 8), tg(64, 64);
    convT2048<<<tg, tb, 0, stream>>>(Wq, WqkvT);
    convT2048<<<tg, tb, 0, stream>>>(Wk, WqkvT + 2048 * 2048);
    convT2048<<<tg, tb, 0, stream>>>(Wv, WqkvT + 2 * 2048 * 2048);
    convT2048<<<tg, tb, 0, stream>>>(Wo, WoT);

    if (bigws) {
        cvt_bf16<<<16384, 256, 0, stream>>>(x, xbf);
        // fused QKV: [16384][2048] @ [6144][2048]^T -> [16384][6144]
        gemm_bt<ushort, 6144><<<6144, 256, 0, stream>>>(
            xbf, 2048, WqkvT, bq, bk, bv, nullptr, qkv);
    } else {
        gemm_f32a<6144><<<6144, 256, 0, stream>>>(
            x, 2048, WqkvT, bq, bk, bv, qkv);
    }

    attn_kernel<<<4096, 256, 0, stream>>>(qkv);

    // attended lives in q-slice of fused buffer (lda=6144)
    gemm_bt<float, 2048><<<2048, 256, 0, stream>>>(
        qkv, 6144, WoT, bo, bo, bo, x, out);

    ln_kernel<<<16384, 256, 0, stream>>>(out, gamma, beta);
}

// Round 3
// 1041.250 us; speedup vs baseline: 1.1361x; 1.0741x over previous
//
#include <hip/hip_runtime.h>
#include <hip/hip_bf16.h>
#include <stdint.h>

// SelfAttentionBlock: B=4,S=4096,C=2048,O=2048,H=8,DH=256
//
// R3: GEMMs ported from the m97 128²/2-barrier structure (ceiling ~912 TF,
// we measured 797) to the 256² 8-phase counted-vmcnt template (m201-style):
//   - BM=BN=256, BK=64, 512 threads = 8 waves (2M x 4N), per-wave C 128x64.
//   - LDS 128KB: lA[2][256][64] + lB[2][256][64] bf16 (double-buffered).
//   - Per K-tile: 4 phases x 16 MFMA. Phases 1-2 preload ALL 24 fragments
//     (12 ds_read_b128 each) -> db[c] fully retired at phase-2 barrier.
//   - Staging (2 x global_load_lds per phase): B0(kt+1),B1(kt+1) -> db[c^1]
//     in ph1/2 (safe: db[c^1] retired since kt-1 ph2); A0(kt+2),A1(kt+2)
//     -> db[c] in ph3/4 (safe: db[c] retired at ph2-close barrier).
//   - Boundary wait: s_waitcnt vmcnt(4) (2 half-tiles in flight) - never 0
//     in steady state (T4). Raw s_barrier (no __syncthreads vmcnt-drain).
//   - T2 swizzle: LDS dest linear (DMA requirement), global SOURCE column
//     pre-swizzled slot^=(row&7), ds_read applies same XOR -> 2-way max.
//   - T5 setprio(1) around each MFMA cluster.
//
// Pipeline (path X, ws >= 288MB):
//   0) x (fp32) -> xbf (bf16)
//   1) transpose+convert Wq|Wk|Wv -> WqkvT bf16 [6144][2048]; Wo -> WoT
//   2) qkv = xbf @ Wqkv + b      (gemm256<N=6144>, grid 1536, XCD N-stripe)
//   3) per-position 8-head attention in fused buffer (attended -> q-slice)
//   4) y = attended @ Wo + bo + x -> out fp32 (gemm256<N=2048>, lda=6144)
//   5) LayerNorm in place on out
// Path Y (ws < 288MB): QKV GEMM uses gemm_f32a (old 128² structure); rest same.

using short8  = __attribute__((ext_vector_type(8))) short;
using floatx4 = __attribute__((ext_vector_type(4))) float;

__device__ __forceinline__ float bf2f(ushort u) {
    union { uint32_t i; float f; } v; v.i = ((uint32_t)u) << 16; return v.f;
}
__device__ __forceinline__ ushort f2bf(float f) {
    union { float f; uint32_t i; } v; v.f = f;
    uint32_t r = v.i + 0x7fffu + ((v.i >> 16) & 1u);
    return (ushort)(r >> 16);
}
__device__ __forceinline__ short8 pack8(const floatx4& a, const floatx4& b) {
    short8 o;
    o[0] = (short)f2bf(a[0]); o[1] = (short)f2bf(a[1]);
    o[2] = (short)f2bf(a[2]); o[3] = (short)f2bf(a[3]);
    o[4] = (short)f2bf(b[0]); o[5] = (short)f2bf(b[1]);
    o[6] = (short)f2bf(b[2]); o[7] = (short)f2bf(b[3]);
    return o;
}
__device__ __forceinline__ void async_copy16(const void* g, void* l) {
    __builtin_amdgcn_global_load_lds(
        (__attribute__((address_space(1))) uint32_t*)g,
        (__attribute__((address_space(3))) uint32_t*)l,
        16, 0, 0);
}

#define GBAR do { asm volatile("" ::: "memory"); \
                  __builtin_amdgcn_s_barrier(); \
                  asm volatile("" ::: "memory"); } while (0)
#define LGKM0 asm volatile("s_waitcnt lgkmcnt(0)" ::: "memory")

// -------- fp32 -> bf16 bulk convert (8 elems/thread) ------------------------
__global__ void cvt_bf16(const float* __restrict__ in, ushort* __restrict__ out) {
    const size_t base = ((size_t)blockIdx.x * 256 + threadIdx.x) * 8;
    floatx4 a = *(const floatx4*)&in[base];
    floatx4 b = *(const floatx4*)&in[base + 4];
    *(short8*)&out[base] = pack8(a, b);
}

// -------- weight transpose+convert: fp32 [2048][2048] -> bf16 T -------------
__global__ void convT2048(const float* __restrict__ in, ushort* __restrict__ out) {
    __shared__ alignas(16) float tile[32][33];
    const int x = blockIdx.x * 32 + threadIdx.x;
    const int y0 = blockIdx.y * 32;
    for (int j = threadIdx.y; j < 32; j += 8)
        tile[j][threadIdx.x] = in[(size_t)(y0 + j) * 2048 + x];
    __syncthreads();
    const int x2 = blockIdx.y * 32 + threadIdx.x;
    const int y2 = blockIdx.x * 32;
    for (int j = threadIdx.y; j < 32; j += 8)
        out[(size_t)(y2 + j) * 2048 + x2] = f2bf(tile[threadIdx.x][j]);
}

// -------- 256² 8-phase GEMM: C[M][N] = A_bf16[M][2048](lda) @ Bt^T + bias ---
template <typename CT, int N>
__global__ __launch_bounds__(512, 2)
void gemm256(const ushort* __restrict__ A, int lda,
             const ushort* __restrict__ Bt,
             const float* __restrict__ b0, const float* __restrict__ b1,
             const float* __restrict__ b2,
             const float* __restrict__ resid, CT* __restrict__ C)
{
    constexpr int K   = 2048;
    constexpr int NKT = K / 64;       // 32 K-tiles
    constexpr int NT  = N / 256;      // N-tiles
    constexpr int SW  = NT / 8;       // stripe width per XCD
    __shared__ alignas(16) ushort lA[2][256 * 64];   // 64KB
    __shared__ alignas(16) ushort lB[2][256 * 64];   // 64KB

    const int t    = threadIdx.x;
    const int wid  = t >> 6, lane = t & 63;
    const int wr   = wid >> 2, wc = wid & 3;         // 2M x 4N waves
    const int lr   = lane & 15, q4 = lane >> 4;
    const int swk  = lr & 7;                          // read-side swizzle key

    // XCD N-stripe decode (each XCD owns SW B-panels, L2-resident; A via L3)
    const int l    = (int)blockIdx.x;
    const int xcd  = l & 7;
    const int j2   = l >> 3;
    const int row0 = (j2 / SW) * 256;
    const int col0 = (xcd * SW + (j2 % SW)) * 256;

    const float* bias; int boff;
    if (col0 < 2048)      { bias = b0; boff = 0; }
    else if (col0 < 4096) { bias = b1; boff = 2048; }
    else                  { bias = b2; boff = 4096; }

    // ---- staging constants: half-tile = 128 rows x 64 cols = 16KB =
    // 512 thr x 2 chunks x 16B. chunk ci: u=ci*512+t, row=u>>3, slot=u&7.
    // LDS dest linear (u*16B); global source col pre-swizzled (rule #21).
    const int rpb = t >> 3;                 // row 0..63 (chunk1: +64)
    const int sp  = t & 7;
    const int gc0 = (sp ^ (rpb & 7)) * 8;   // (rpb+64)&7 == rpb&7
    const ushort* pA0 = A  + (size_t)(row0 + rpb)      * lda + gc0;
    const ushort* pA1 = A  + (size_t)(row0 + 64 + rpb) * lda + gc0;
    const ushort* pB0 = Bt + (size_t)(col0 + rpb)      * K   + gc0;
    const ushort* pB1 = Bt + (size_t)(col0 + 64 + rpb) * K   + gc0;

#define STAGE_A(buf, half, kn) do { \
    async_copy16(pA0 + (size_t)(half) * 128 * lda + (kn) * 64, \
                 &lA[buf][(half) * 8192 + t * 8]); \
    async_copy16(pA1 + (size_t)(half) * 128 * lda + (kn) * 64, \
                 &lA[buf][(half) * 8192 + 4096 + t * 8]); \
} while (0)
#define STAGE_B(buf, half, kn) do { \
    async_copy16(pB0 + (size_t)(half) * 128 * K + (kn) * 64, \
                 &lB[buf][(half) * 8192 + t * 8]); \
    async_copy16(pB1 + (size_t)(half) * 128 * K + (kn) * 64, \
                 &lB[buf][(half) * 8192 + 4096 + t * 8]); \
} while (0)

    // ---- fragment read addressing (row*64 ushort + swizzled 16B slot)
    const int arow = (wr * 128 + lr) * 64;
    const int brow = (wc * 64  + lr) * 64;
    const int c0 = ((0 + q4) ^ swk) * 8;    // ks=0 slot
    const int c1 = ((4 + q4) ^ swk) * 8;    // ks=1 slot

    floatx4 acc[8][4];
    #pragma unroll
    for (int i = 0; i < 8; i++)
        #pragma unroll
        for (int j = 0; j < 4; j++)
            acc[i][j] = (floatx4){0.f, 0.f, 0.f, 0.f};

    // ---- prologue: K-tile 0 fully + A-halves of K-tile 1 in flight
    STAGE_A(0, 0, 0); STAGE_A(0, 1, 0);
    STAGE_B(0, 0, 0); STAGE_B(0, 1, 0);
    STAGE_A(1, 0, 1); STAGE_A(1, 1, 1);
    asm volatile("s_waitcnt vmcnt(4)" ::: "memory");   // K-tile 0 landed
    GBAR;

    short8 af[8][2], bf[4][2];

    for (int kt = 0; kt < NKT; ++kt) {
        const int c = kt & 1;

        // ---- phase 1: preload m0-3 frags + n0-1 frags (12 ds_read_b128)
        #pragma unroll
        for (int i = 0; i < 4; i++) {
            af[i][0] = *(const short8*)&lA[c][arow + i * 1024 + c0];
            af[i][1] = *(const short8*)&lA[c][arow + i * 1024 + c1];
        }
        #pragma unroll
        for (int j = 0; j < 2; j++) {
            bf[j][0] = *(const short8*)&lB[c][brow + j * 1024 + c0];
            bf[j][1] = *(const short8*)&lB[c][brow + j * 1024 + c1];
        }
        if (kt < NKT - 1) STAGE_B(c ^ 1, 0, kt + 1);
        GBAR; LGKM0;
        __builtin_amdgcn_s_setprio(1);
        #pragma unroll
        for (int i = 0; i < 4; i++)
            #pragma unroll
            for (int j = 0; j < 2; j++)
                #pragma unroll
                for (int ks = 0; ks < 2; ks++)
                    acc[i][j] = __builtin_amdgcn_mfma_f32_16x16x32_bf16(
                        af[i][ks], bf[j][ks], acc[i][j], 0, 0, 0);
        __builtin_amdgcn_s_setprio(0);
        GBAR;

        // ---- phase 2: preload m4-7 + n2-3 (db[c] fully read after this)
        #pragma unroll
        for (int i = 4; i < 8; i++) {
            af[i][0] = *(const short8*)&lA[c][arow + i * 1024 + c0];
            af[i][1] = *(const short8*)&lA[c][arow + i * 1024 + c1];
        }
        #pragma unroll
        for (int j = 2; j < 4; j++) {
            bf[j][0] = *(const short8*)&lB[c][brow + j * 1024 + c0];
            bf[j][1] = *(const short8*)&lB[c][brow + j * 1024 + c1];
        }
        if (kt < NKT - 1) STAGE_B(c ^ 1, 1, kt + 1);
        GBAR; LGKM0;
        __builtin_amdgcn_s_setprio(1);
        #pragma unroll
        for (int i = 4; i < 8; i++)
            #pragma unroll
            for (int j = 2; j < 4; j++)
                #pragma unroll
                for (int ks = 0; ks < 2; ks++)
                    acc[i][j] = __builtin_amdgcn_mfma_f32_16x16x32_bf16(
                        af[i][ks], bf[j][ks], acc[i][j], 0, 0, 0);
        __builtin_amdgcn_s_setprio(0);
        GBAR;   // all waves' reads of db[c] complete -> ph3/4 may overwrite it

        // ---- phase 3: stage A0(kt+2) into db[c]; MFMA m0-3 x n2-3 (regs)
        if (kt < NKT - 2) STAGE_A(c, 0, kt + 2);
        __builtin_amdgcn_s_setprio(1);
        #pragma unroll
        for (int i = 0; i < 4; i++)
            #pragma unroll
            for (int j = 2; j < 4; j++)
                #pragma unroll
                for (int ks = 0; ks < 2; ks++)
                    acc[i][j] = __builtin_amdgcn_mfma_f32_16x16x32_bf16(
                        af[i][ks], bf[j][ks], acc[i][j], 0, 0, 0);
        __builtin_amdgcn_s_setprio(0);
        GBAR;

        // ---- phase 4: stage A1(kt+2); MFMA m4-7 x n0-1; boundary wait
        if (kt < NKT - 2) STAGE_A(c, 1, kt + 2);
        __builtin_amdgcn_s_setprio(1);
        #pragma unroll
        for (int i = 4; i < 8; i++)
            #pragma unroll
            for (int j = 0; j < 2; j++)
                #pragma unroll
                for (int ks = 0; ks < 2; ks++)
                    acc[i][j] = __builtin_amdgcn_mfma_f32_16x16x32_bf16(
                        af[i][ks], bf[j][ks], acc[i][j], 0, 0, 0);
        __builtin_amdgcn_s_setprio(0);
        // counted boundary wait: next K-tile fully landed, 2 half-tiles
        // (A-halves of kt+2, 4 loads) stay in flight across the barrier
        if (kt < NKT - 2)       { asm volatile("s_waitcnt vmcnt(4)" ::: "memory"); }
        else if (kt == NKT - 2) { asm volatile("s_waitcnt vmcnt(0)" ::: "memory"); }
        if (kt < NKT - 1) GBAR;
    }
#undef STAGE_A
#undef STAGE_B

    // ---- epilogue: C[row0+wr*128+i*16+q4*4+r][col0+wc*64+j*16+lr]
    #pragma unroll
    for (int j = 0; j < 4; j++) {
        const int gcol = col0 + wc * 64 + j * 16 + lr;
        const float bv = bias[gcol - boff];
        #pragma unroll
        for (int i = 0; i < 8; i++) {
            #pragma unroll
            for (int r = 0; r < 4; r++) {
                const int grow = row0 + wr * 128 + i * 16 + q4 * 4 + r;
                const size_t off = (size_t)grow * N + gcol;
                float v = acc[i][j][r] + bv;
                if (resid) v += resid[off];
                if constexpr (__is_same(CT, float)) C[off] = v;
                else                                C[off] = f2bf(v);
            }
        }
    }
}

// -------- fallback GEMM (path Y): fp32 A staged raw, old 128² structure -----
template <int N>
__global__ __launch_bounds__(256, 2)
void gemm_f32a(const float* __restrict__ A, int lda,
               const ushort* __restrict__ Bt,
               const float* __restrict__ b0, const float* __restrict__ b1,
               const float* __restrict__ b2, ushort* __restrict__ C)
{
    constexpr int K = 2048;
    constexpr int NT = N / 128;
    constexpr int SW = NT / 8;
    __shared__ alignas(16) float  lA32[128 * 32];   // 16KB
    __shared__ alignas(16) ushort lB[128 * 32];     // 8KB

    const int t = threadIdx.x;
    const int wave = t >> 6, lane = t & 63;

    const int l = (int)blockIdx.x;
    const int xcd = l & 7;
    const int j2 = l >> 3;
    const int row0 = (j2 / SW) * 128;
    const int col0 = (xcd * SW + (j2 % SW)) * 128;

    const float* bias; int boff;
    if (col0 < 2048)      { bias = b0; boff = 0; }
    else if (col0 < 4096) { bias = b1; boff = 2048; }
    else                  { bias = b2; boff = 4096; }

    const int ar = t >> 3, ac = (t & 7) * 4;
    const float* gA0 = A + (size_t)(row0 + ar) * lda + ac;
    const ushort* gB0 = Bt + (size_t)(col0 + (t >> 2)) * K + (t & 3) * 8;
    const ushort* gB1 = Bt + (size_t)(col0 + 64 + (t >> 2)) * K + (t & 3) * 8;

    const int wm = (wave >> 1) * 64;
    const int wn = (wave & 1) * 64;
    const int q4 = lane >> 4;
    const int lr = lane & 15;

    floatx4 acc[4][4];
    #pragma unroll
    for (int i = 0; i < 4; i++)
        #pragma unroll
        for (int j = 0; j < 4; j++)
            acc[i][j] = (floatx4){0.f, 0.f, 0.f, 0.f};

    for (int kt = 0; kt < K / 32; ++kt) {
        const int ko = kt * 32;
        #pragma unroll
        for (int n = 0; n < 4; n++)
            async_copy16(gA0 + (size_t)n * 32 * lda + ko, &lA32[(n * 256 + t) * 4]);
        async_copy16(gB0 + ko, &lB[t * 8]);
        async_copy16(gB1 + ko, &lB[2048 + t * 8]);
        __syncthreads();

        short8 af[4], bfr[4];
        #pragma unroll
        for (int i = 0; i < 4; i++) {
            const floatx4* pa = (const floatx4*)&lA32[(wm + i * 16 + lr) * 32 + q4 * 8];
            af[i] = pack8(pa[0], pa[1]);
        }
        #pragma unroll
        for (int j = 0; j < 4; j++)
            bfr[j] = *(const short8*)&lB[(wn + j * 16 + lr) * 32 + q4 * 8];

        #pragma unroll
        for (int i = 0; i < 4; i++)
            #pragma unroll
            for (int j = 0; j < 4; j++)
                acc[i][j] = __builtin_amdgcn_mfma_f32_16x16x32_bf16(
                    af[i], bfr[j], acc[i][j], 0, 0, 0);
        __syncthreads();
    }

    #pragma unroll
    for (int j = 0; j < 4; j++) {
        const int gcol = col0 + wn + j * 16 + lr;
        const float bv = bias[gcol - boff];
        #pragma unroll
        for (int i = 0; i < 4; i++)
            #pragma unroll
            for (int r = 0; r < 4; r++) {
                const int grow = row0 + wm + i * 16 + q4 * 4 + r;
                C[(size_t)grow * N + gcol] = f2bf(acc[i][j][r] + bv);
            }
    }
}

// -------- per-position attention on fused qkv [16384][6144], bf16 ----------
__global__ __launch_bounds__(256, 2)
void attn_kernel(ushort* __restrict__ qkv)
{
    __shared__ alignas(16) ushort sq[4][2048];
    __shared__ alignas(16) ushort sk[4][2048];
    __shared__ alignas(16) ushort sv[4][2048];
    const int wave = threadIdx.x >> 6, lane = threadIdx.x & 63;
    const size_t p = (size_t)blockIdx.x * 4 + wave;
    const size_t base = p * 6144;

    #pragma unroll
    for (int c = 0; c < 4; c++) {
        const int idx = c * 512 + lane * 8;
        *(short8*)&sq[wave][idx] = *(const short8*)&qkv[base + idx];
        *(short8*)&sk[wave][idx] = *(const short8*)&qkv[base + 2048 + idx];
        *(short8*)&sv[wave][idx] = *(const short8*)&qkv[base + 4096 + idx];
    }

    const int h = lane >> 3;
    const int tt = lane & 7;
    float s = 0.f;
    #pragma unroll 4
    for (int c = 0; c < 32; c++) {
        short8 qv = *(const short8*)&sq[wave][h * 256 + c * 8];
        short8 kv = *(const short8*)&sk[wave][tt * 256 + c * 8];
        #pragma unroll
        for (int e = 0; e < 8; e++)
            s += bf2f((ushort)qv[e]) * bf2f((ushort)kv[e]);
    }
    s *= (1.0f / 16.0f);   // 1/sqrt(256)

    float m = s;
    m = fmaxf(m, __shfl_xor(m, 1));
    m = fmaxf(m, __shfl_xor(m, 2));
    m = fmaxf(m, __shfl_xor(m, 4));
    float e = __expf(s - m);
    float sum = e;
    sum += __shfl_xor(sum, 1);
    sum += __shfl_xor(sum, 2);
    sum += __shfl_xor(sum, 4);
    const float w = e / sum;

    float wt[8];
    #pragma unroll
    for (int t2 = 0; t2 < 8; t2++)
        wt[t2] = __shfl(w, (lane & 56) + t2);

    const int d0 = (lane & 7) * 8;
    #pragma unroll
    for (int c = 0; c < 4; c++) {
        const int d = d0 + c * 64;
        float acc[8] = {0, 0, 0, 0, 0, 0, 0, 0};
        #pragma unroll
        for (int t2 = 0; t2 < 8; t2++) {
            short8 vv = *(const short8*)&sv[wave][t2 * 256 + d];
            #pragma unroll
            for (int e2 = 0; e2 < 8; e2++)
                acc[e2] += wt[t2] * bf2f((ushort)vv[e2]);
        }
        short8 o;
        #pragma unroll
        for (int e2 = 0; e2 < 8; e2++)
            o[e2] = (short)f2bf(acc[e2]);
        *(short8*)&qkv[base + h * 256 + d] = o;
    }
}

// -------- LayerNorm over C=2048, fp32 in place on d_out ---------------------
__global__ __launch_bounds__(256, 2)
void ln_kernel(float* __restrict__ y, const float* __restrict__ gamma,
               const float* __restrict__ beta)
{
    __shared__ float red[2][4];
    const int t = threadIdx.x;
    const size_t base = (size_t)blockIdx.x * 2048 + t * 8;
    floatx4 a = *(const floatx4*)&y[base];
    floatx4 b = *(const floatx4*)&y[base + 4];
    float f[8] = {a[0], a[1], a[2], a[3], b[0], b[1], b[2], b[3]};
    float s = 0.f, ss = 0.f;
    #pragma unroll
    for (int e = 0; e < 8; e++) { s += f[e]; ss += f[e] * f[e]; }
    #pragma unroll
    for (int off = 1; off < 64; off <<= 1) {
        s  += __shfl_xor(s, off);
        ss += __shfl_xor(ss, off);
    }
    const int wave = t >> 6, lane = t & 63;
    if (lane == 0) { red[0][wave] = s; red[1][wave] = ss; }
    __syncthreads();
    s  = red[0][0] + red[0][1] + red[0][2] + red[0][3];
    ss = red[1][0] + red[1][1] + red[1][2] + red[1][3];
    const float mu  = s * (1.f / 2048.f);
    const float var = fmaxf(ss * (1.f / 2048.f) - mu * mu, 0.f);
    const float rs  = rsqrtf(var + 1e-5f);
    floatx4 g0 = *(const floatx4*)&gamma[t * 8];
    floatx4 g1 = *(const floatx4*)&gamma[t * 8 + 4];
    floatx4 b0 = *(const floatx4*)&beta[t * 8];
    floatx4 b1 = *(const floatx4*)&beta[t * 8 + 4];
    floatx4 o0, o1;
    #pragma unroll
    for (int e = 0; e < 4; e++) {
        o0[e] = g0[e] * (f[e] - mu) * rs + b0[e];
        o1[e] = g1[e] * (f[e + 4] - mu) * rs + b1[e];
    }
    *(floatx4*)&y[base]     = o0;
    *(floatx4*)&y[base + 4] = o1;
}

extern "C" void kernel_launch(void* const* d_in, const int* in_sizes, int n_in,
                              void* d_out, int out_size, void* d_ws, size_t ws_size,
                              hipStream_t stream)
{
    const float* x     = (const float*)d_in[0];
    const float* Wq    = (const float*)d_in[1];
    const float* bq    = (const float*)d_in[2];
    const float* Wk    = (const float*)d_in[3];
    const float* bk    = (const float*)d_in[4];
    const float* Wv    = (const float*)d_in[5];
    const float* bv    = (const float*)d_in[6];
    const float* Wo    = (const float*)d_in[7];
    const float* bo    = (const float*)d_in[8];
    const float* gamma = (const float*)d_in[9];
    const float* beta  = (const float*)d_in[10];
    float* out = (float*)d_out;

    char* ws = (char*)d_ws;
    const size_t MB = 1024 * 1024;
    ushort* WqkvT = (ushort*)(ws + 0 * MB);    // 24MB: Wq^T | Wk^T | Wv^T rows
    ushort* WoT   = (ushort*)(ws + 24 * MB);   // 8MB

    const bool bigws = ws_size >= 288 * MB;
    ushort* xbf = (ushort*)(ws + 32 * MB);                      // path X: 64MB
    ushort* qkv = (ushort*)(ws + (bigws ? 96 : 32) * MB);       // 192MB fused

    dim3 tb(32, 8), tg(64, 64);
    convT2048<<<tg, tb, 0, stream>>>(Wq, WqkvT);
    convT2048<<<tg, tb, 0, stream>>>(Wk, WqkvT + 2048 * 2048);
    convT2048<<<tg, tb, 0, stream>>>(Wv, WqkvT + 2 * 2048 * 2048);
    convT2048<<<tg, tb, 0, stream>>>(Wo, WoT);

    if (bigws) {
        cvt_bf16<<<16384, 256, 0, stream>>>(x, xbf);
        // fused QKV: [16384][2048] @ [6144][2048]^T -> [16384][6144]
        gemm256<ushort, 6144><<<1536, 512, 0, stream>>>(
            xbf, 2048, WqkvT, bq, bk, bv, nullptr, qkv);
    } else {
        gemm_f32a<6144><<<6144, 256, 0, stream>>>(
            x, 2048, WqkvT, bq, bk, bv, qkv);
    }

    attn_kernel<<<4096, 256, 0, stream>>>(qkv);

    // attended lives in q-slice of fused buffer (lda=6144)
    gemm256<float, 2048><<<512, 512, 0, stream>>>(
        qkv, 6144, WoT, bo, bo, bo, x, out);

    ln_kernel<<<16384, 256, 0, stream>>>(out, gamma, beta);
}

// Round 4
// 1027.623 us; speedup vs baseline: 1.1512x; 1.0133x over previous
//
#include <hip/hip_runtime.h>
#include <hip/hip_bf16.h>
#include <stdint.h>

// SelfAttentionBlock: B=4,S=4096,C=2048,O=2048,H=8,DH=256
//
// R4: gemm256 schedule refined (R3 was 12/12/0/0 ds_read clustering ->
// lgkmcnt(0)-on-12 stall after each ph1/ph2 barrier). Now m-quarter phases
// with A-reads pipelined one phase ahead + counted waits:
//   ph1: read B(8)+Aq0(4)+Aq1(4); STAGE_B(kt+1,h0); bar; MFMA q0
//   ph2: read Aq2(4);             STAGE_B(kt+1,h1); bar; MFMA q1
//   ph3: read Aq3(4);                               bar; MFMA q2
//   ph4: lgkm0; bar; STAGE_A(kt+2,h0+h1); MFMA q3; vmcnt(4); bar
// DMA ledger: in-flight at boundary = A(kt+1)4+B(kt+1)4+A(kt+2)4 = 12;
// vmcnt(4) retires A(kt+1),B(kt+1) (needed for kt+1), leaves A(kt+2).
// Overwrite safety: B(kt+1)->db[c^1] after kt-1 ph4 lgkm0+bar; A(kt+2)->db[c]
// after kt ph4 lgkm0+bar. Tail: vmcnt(0) at kt=NKT-2.
// Kept from R3: T2 swizzle (conflicts==0), XCD N-stripe, T5 setprio, 128KB dbuf.
//
// Pipeline (path X, ws >= 288MB):
//   0) x (fp32) -> xbf (bf16)
//   1) transpose+convert Wq|Wk|Wv -> WqkvT bf16 [6144][2048]; Wo -> WoT
//   2) qkv = xbf @ Wqkv + b      (gemm256<N=6144>, grid 1536)
//   3) per-position 8-head attention in fused buffer (attended -> q-slice)
//   4) y = attended @ Wo + bo + x -> out fp32 (gemm256<N=2048>, lda=6144)
//   5) LayerNorm in place on out
// Path Y (ws < 288MB): QKV GEMM uses gemm_f32a (old 128² structure).

using short8  = __attribute__((ext_vector_type(8))) short;
using floatx4 = __attribute__((ext_vector_type(4))) float;

__device__ __forceinline__ float bf2f(ushort u) {
    union { uint32_t i; float f; } v; v.i = ((uint32_t)u) << 16; return v.f;
}
__device__ __forceinline__ ushort f2bf(float f) {
    union { float f; uint32_t i; } v; v.f = f;
    uint32_t r = v.i + 0x7fffu + ((v.i >> 16) & 1u);
    return (ushort)(r >> 16);
}
__device__ __forceinline__ short8 pack8(const floatx4& a, const floatx4& b) {
    short8 o;
    o[0] = (short)f2bf(a[0]); o[1] = (short)f2bf(a[1]);
    o[2] = (short)f2bf(a[2]); o[3] = (short)f2bf(a[3]);
    o[4] = (short)f2bf(b[0]); o[5] = (short)f2bf(b[1]);
    o[6] = (short)f2bf(b[2]); o[7] = (short)f2bf(b[3]);
    return o;
}
__device__ __forceinline__ void async_copy16(const void* g, void* l) {
    __builtin_amdgcn_global_load_lds(
        (__attribute__((address_space(1))) uint32_t*)g,
        (__attribute__((address_space(3))) uint32_t*)l,
        16, 0, 0);
}

#define GBAR do { asm volatile("" ::: "memory"); \
                  __builtin_amdgcn_s_barrier(); \
                  asm volatile("" ::: "memory"); } while (0)
#define LGKM0 asm volatile("s_waitcnt lgkmcnt(0)" ::: "memory")

// -------- fp32 -> bf16 bulk convert (8 elems/thread) ------------------------
__global__ void cvt_bf16(const float* __restrict__ in, ushort* __restrict__ out) {
    const size_t base = ((size_t)blockIdx.x * 256 + threadIdx.x) * 8;
    floatx4 a = *(const floatx4*)&in[base];
    floatx4 b = *(const floatx4*)&in[base + 4];
    *(short8*)&out[base] = pack8(a, b);
}

// -------- weight transpose+convert: fp32 [2048][2048] -> bf16 T -------------
__global__ void convT2048(const float* __restrict__ in, ushort* __restrict__ out) {
    __shared__ alignas(16) float tile[32][33];
    const int x = blockIdx.x * 32 + threadIdx.x;
    const int y0 = blockIdx.y * 32;
    for (int j = threadIdx.y; j < 32; j += 8)
        tile[j][threadIdx.x] = in[(size_t)(y0 + j) * 2048 + x];
    __syncthreads();
    const int x2 = blockIdx.y * 32 + threadIdx.x;
    const int y2 = blockIdx.x * 32;
    for (int j = threadIdx.y; j < 32; j += 8)
        out[(size_t)(y2 + j) * 2048 + x2] = f2bf(tile[threadIdx.x][j]);
}

// -------- 256² 8-phase GEMM: C[M][N] = A_bf16[M][2048](lda) @ Bt^T + bias ---
template <typename CT, int N>
__global__ __launch_bounds__(512, 2)
void gemm256(const ushort* __restrict__ A, int lda,
             const ushort* __restrict__ Bt,
             const float* __restrict__ b0, const float* __restrict__ b1,
             const float* __restrict__ b2,
             const float* __restrict__ resid, CT* __restrict__ C)
{
    constexpr int K   = 2048;
    constexpr int NKT = K / 64;       // 32 K-tiles
    constexpr int NT  = N / 256;      // N-tiles
    constexpr int SW  = NT / 8;       // stripe width per XCD
    __shared__ alignas(16) ushort lA[2][256 * 64];   // 64KB
    __shared__ alignas(16) ushort lB[2][256 * 64];   // 64KB

    const int t    = threadIdx.x;
    const int wid  = t >> 6, lane = t & 63;
    const int wr   = wid >> 2, wc = wid & 3;         // 2M x 4N waves
    const int lr   = lane & 15, q4 = lane >> 4;
    const int swk  = lr & 7;                          // read-side swizzle key

    // XCD N-stripe decode (each XCD owns SW B-panels, L2-resident; A via L3)
    const int l    = (int)blockIdx.x;
    const int xcd  = l & 7;
    const int j2   = l >> 3;
    const int row0 = (j2 / SW) * 256;
    const int col0 = (xcd * SW + (j2 % SW)) * 256;

    const float* bias; int boff;
    if (col0 < 2048)      { bias = b0; boff = 0; }
    else if (col0 < 4096) { bias = b1; boff = 2048; }
    else                  { bias = b2; boff = 4096; }

    // ---- staging: half-tile = 128 rows x 64 cols = 16KB = 512 thr x 16B.
    // LDS dest linear; global source col pre-swizzled (rule #21).
    const int rpb = t >> 3;                 // row 0..63 (chunk1: +64)
    const int sp  = t & 7;
    const int gc0 = (sp ^ (rpb & 7)) * 8;   // (rpb+64)&7 == rpb&7
    const ushort* pA0 = A  + (size_t)(row0 + rpb)      * lda + gc0;
    const ushort* pA1 = A  + (size_t)(row0 + 64 + rpb) * lda + gc0;
    const ushort* pB0 = Bt + (size_t)(col0 + rpb)      * K   + gc0;
    const ushort* pB1 = Bt + (size_t)(col0 + 64 + rpb) * K   + gc0;

#define STAGE_A(buf, half, kn) do { \
    async_copy16(pA0 + (size_t)(half) * 128 * lda + (kn) * 64, \
                 &lA[buf][(half) * 8192 + t * 8]); \
    async_copy16(pA1 + (size_t)(half) * 128 * lda + (kn) * 64, \
                 &lA[buf][(half) * 8192 + 4096 + t * 8]); \
} while (0)
#define STAGE_B(buf, half, kn) do { \
    async_copy16(pB0 + (size_t)(half) * 128 * K + (kn) * 64, \
                 &lB[buf][(half) * 8192 + t * 8]); \
    async_copy16(pB1 + (size_t)(half) * 128 * K + (kn) * 64, \
                 &lB[buf][(half) * 8192 + 4096 + t * 8]); \
} while (0)

    // ---- fragment read addressing (row*64 ushort + swizzled 16B slot)
    const int arow = (wr * 128 + lr) * 64;
    const int brow = (wc * 64  + lr) * 64;
    const int c0 = ((0 + q4) ^ swk) * 8;    // ks=0 slot
    const int c1 = ((4 + q4) ^ swk) * 8;    // ks=1 slot

    floatx4 acc[8][4];
    #pragma unroll
    for (int i = 0; i < 8; i++)
        #pragma unroll
        for (int j = 0; j < 4; j++)
            acc[i][j] = (floatx4){0.f, 0.f, 0.f, 0.f};

    // ---- prologue: K-tile 0 fully + A-halves of K-tile 1 in flight
    STAGE_A(0, 0, 0); STAGE_A(0, 1, 0);
    STAGE_B(0, 0, 0); STAGE_B(0, 1, 0);
    STAGE_A(1, 0, 1); STAGE_A(1, 1, 1);
    asm volatile("s_waitcnt vmcnt(4)" ::: "memory");   // K-tile 0 landed
    GBAR;

    short8 bf[4][2];
    short8 aq[4][2][2];   // [quarter][m-in-quarter][ks]

#define LOAD_AQ(q) do { \
    _Pragma("unroll") \
    for (int m = 0; m < 2; m++) { \
        aq[q][m][0] = *(const short8*)&lA[c][arow + ((q) * 2 + m) * 1024 + c0]; \
        aq[q][m][1] = *(const short8*)&lA[c][arow + ((q) * 2 + m) * 1024 + c1]; \
    } \
} while (0)
#define MFMA_Q(q) do { \
    _Pragma("unroll") \
    for (int m = 0; m < 2; m++) \
        _Pragma("unroll") \
        for (int j = 0; j < 4; j++) \
            _Pragma("unroll") \
            for (int ks = 0; ks < 2; ks++) \
                acc[(q) * 2 + m][j] = __builtin_amdgcn_mfma_f32_16x16x32_bf16( \
                    aq[q][m][ks], bf[j][ks], acc[(q) * 2 + m][j], 0, 0, 0); \
} while (0)

    for (int kt = 0; kt < NKT; ++kt) {
        const int c = kt & 1;

        // ---- phase 1: B(8) + Aq0(4) + Aq1(4); MFMA q0 (counted waits:
        // issue order Bn01, Aq0, Bn23, Aq1 -> q0's first MFMAs start early)
        #pragma unroll
        for (int j = 0; j < 2; j++) {
            bf[j][0] = *(const short8*)&lB[c][brow + j * 1024 + c0];
            bf[j][1] = *(const short8*)&lB[c][brow + j * 1024 + c1];
        }
        LOAD_AQ(0);
        #pragma unroll
        for (int j = 2; j < 4; j++) {
            bf[j][0] = *(const short8*)&lB[c][brow + j * 1024 + c0];
            bf[j][1] = *(const short8*)&lB[c][brow + j * 1024 + c1];
        }
        LOAD_AQ(1);
        if (kt < NKT - 1) STAGE_B(c ^ 1, 0, kt + 1);
        GBAR;
        __builtin_amdgcn_s_setprio(1);
        MFMA_Q(0);
        __builtin_amdgcn_s_setprio(0);

        // ---- phase 2: Aq2(4); MFMA q1 (frags issued last phase)
        LOAD_AQ(2);
        if (kt < NKT - 1) STAGE_B(c ^ 1, 1, kt + 1);
        GBAR;
        __builtin_amdgcn_s_setprio(1);
        MFMA_Q(1);
        __builtin_amdgcn_s_setprio(0);

        // ---- phase 3: Aq3(4); MFMA q2
        LOAD_AQ(3);
        GBAR;
        __builtin_amdgcn_s_setprio(1);
        MFMA_Q(2);
        __builtin_amdgcn_s_setprio(0);

        // ---- phase 4: all db[c] reads retired -> stage A(kt+2); MFMA q3
        LGKM0;
        GBAR;   // chip-wide: every wave's reads of db[c] done -> safe to DMA
        if (kt < NKT - 2) { STAGE_A(c, 0, kt + 2); STAGE_A(c, 1, kt + 2); }
        __builtin_amdgcn_s_setprio(1);
        MFMA_Q(3);
        __builtin_amdgcn_s_setprio(0);
        // counted boundary wait: A(kt+1),B(kt+1) landed; A(kt+2) in flight
        if (kt < NKT - 2)       { asm volatile("s_waitcnt vmcnt(4)" ::: "memory"); }
        else if (kt == NKT - 2) { asm volatile("s_waitcnt vmcnt(0)" ::: "memory"); }
        if (kt < NKT - 1) GBAR;
    }
#undef STAGE_A
#undef STAGE_B
#undef LOAD_AQ
#undef MFMA_Q

    // ---- epilogue: C[row0+wr*128+i*16+q4*4+r][col0+wc*64+j*16+lr]
    #pragma unroll
    for (int j = 0; j < 4; j++) {
        const int gcol = col0 + wc * 64 + j * 16 + lr;
        const float bv = bias[gcol - boff];
        #pragma unroll
        for (int i = 0; i < 8; i++) {
            #pragma unroll
            for (int r = 0; r < 4; r++) {
                const int grow = row0 + wr * 128 + i * 16 + q4 * 4 + r;
                const size_t off = (size_t)grow * N + gcol;
                float v = acc[i][j][r] + bv;
                if (resid) v += resid[off];
                if constexpr (__is_same(CT, float)) C[off] = v;
                else                                C[off] = f2bf(v);
            }
        }
    }
}

// -------- fallback GEMM (path Y): fp32 A staged raw, old 128² structure -----
template <int N>
__global__ __launch_bounds__(256, 2)
void gemm_f32a(const float* __restrict__ A, int lda,
               const ushort* __restrict__ Bt,
               const float* __restrict__ b0, const float* __restrict__ b1,
               const float* __restrict__ b2, ushort* __restrict__ C)
{
    constexpr int K = 2048;
    constexpr int NT = N / 128;
    constexpr int SW = NT / 8;
    __shared__ alignas(16) float  lA32[128 * 32];   // 16KB
    __shared__ alignas(16) ushort lB[128 * 32];     // 8KB

    const int t = threadIdx.x;
    const int wave = t >> 6, lane = t & 63;

    const int l = (int)blockIdx.x;
    const int xcd = l & 7;
    const int j2 = l >> 3;
    const int row0 = (j2 / SW) * 128;
    const int col0 = (xcd * SW + (j2 % SW)) * 128;

    const float* bias; int boff;
    if (col0 < 2048)      { bias = b0; boff = 0; }
    else if (col0 < 4096) { bias = b1; boff = 2048; }
    else                  { bias = b2; boff = 4096; }

    const int ar = t >> 3, ac = (t & 7) * 4;
    const float* gA0 = A + (size_t)(row0 + ar) * lda + ac;
    const ushort* gB0 = Bt + (size_t)(col0 + (t >> 2)) * K + (t & 3) * 8;
    const ushort* gB1 = Bt + (size_t)(col0 + 64 + (t >> 2)) * K + (t & 3) * 8;

    const int wm = (wave >> 1) * 64;
    const int wn = (wave & 1) * 64;
    const int q4 = lane >> 4;
    const int lr = lane & 15;

    floatx4 acc[4][4];
    #pragma unroll
    for (int i = 0; i < 4; i++)
        #pragma unroll
        for (int j = 0; j < 4; j++)
            acc[i][j] = (floatx4){0.f, 0.f, 0.f, 0.f};

    for (int kt = 0; kt < K / 32; ++kt) {
        const int ko = kt * 32;
        #pragma unroll
        for (int n = 0; n < 4; n++)
            async_copy16(gA0 + (size_t)n * 32 * lda + ko, &lA32[(n * 256 + t) * 4]);
        async_copy16(gB0 + ko, &lB[t * 8]);
        async_copy16(gB1 + ko, &lB[2048 + t * 8]);
        __syncthreads();

        short8 af[4], bfr[4];
        #pragma unroll
        for (int i = 0; i < 4; i++) {
            const floatx4* pa = (const floatx4*)&lA32[(wm + i * 16 + lr) * 32 + q4 * 8];
            af[i] = pack8(pa[0], pa[1]);
        }
        #pragma unroll
        for (int j = 0; j < 4; j++)
            bfr[j] = *(const short8*)&lB[(wn + j * 16 + lr) * 32 + q4 * 8];

        #pragma unroll
        for (int i = 0; i < 4; i++)
            #pragma unroll
            for (int j = 0; j < 4; j++)
                acc[i][j] = __builtin_amdgcn_mfma_f32_16x16x32_bf16(
                    af[i], bfr[j], acc[i][j], 0, 0, 0);
        __syncthreads();
    }

    #pragma unroll
    for (int j = 0; j < 4; j++) {
        const int gcol = col0 + wn + j * 16 + lr;
        const float bv = bias[gcol - boff];
        #pragma unroll
        for (int i = 0; i < 4; i++)
            #pragma unroll
            for (int r = 0; r < 4; r++) {
                const int grow = row0 + wm + i * 16 + q4 * 4 + r;
                C[(size_t)grow * N + gcol] = f2bf(acc[i][j][r] + bv);
            }
    }
}

// -------- per-position attention on fused qkv [16384][6144], bf16 ----------
__global__ __launch_bounds__(256, 2)
void attn_kernel(ushort* __restrict__ qkv)
{
    __shared__ alignas(16) ushort sq[4][2048];
    __shared__ alignas(16) ushort sk[4][2048];
    __shared__ alignas(16) ushort sv[4][2048];
    const int wave = threadIdx.x >> 6, lane = threadIdx.x & 63;
    const size_t p = (size_t)blockIdx.x * 4 + wave;
    const size_t base = p * 6144;

    #pragma unroll
    for (int c = 0; c < 4; c++) {
        const int idx = c * 512 + lane * 8;
        *(short8*)&sq[wave][idx] = *(const short8*)&qkv[base + idx];
        *(short8*)&sk[wave][idx] = *(const short8*)&qkv[base + 2048 + idx];
        *(short8*)&sv[wave][idx] = *(const short8*)&qkv[base + 4096 + idx];
    }

    const int h = lane >> 3;
    const int tt = lane & 7;
    float s = 0.f;
    #pragma unroll 4
    for (int c = 0; c < 32; c++) {
        short8 qv = *(const short8*)&sq[wave][h * 256 + c * 8];
        short8 kv = *(const short8*)&sk[wave][tt * 256 + c * 8];
        #pragma unroll
        for (int e = 0; e < 8; e++)
            s += bf2f((ushort)qv[e]) * bf2f((ushort)kv[e]);
    }
    s *= (1.0f / 16.0f);   // 1/sqrt(256)

    float m = s;
    m = fmaxf(m, __shfl_xor(m, 1));
    m = fmaxf(m, __shfl_xor(m, 2));
    m = fmaxf(m, __shfl_xor(m, 4));
    float e = __expf(s - m);
    float sum = e;
    sum += __shfl_xor(sum, 1);
    sum += __shfl_xor(sum, 2);
    sum += __shfl_xor(sum, 4);
    const float w = e / sum;

    float wt[8];
    #pragma unroll
    for (int t2 = 0; t2 < 8; t2++)
        wt[t2] = __shfl(w, (lane & 56) + t2);

    const int d0 = (lane & 7) * 8;
    #pragma unroll
    for (int c = 0; c < 4; c++) {
        const int d = d0 + c * 64;
        float acc[8] = {0, 0, 0, 0, 0, 0, 0, 0};
        #pragma unroll
        for (int t2 = 0; t2 < 8; t2++) {
            short8 vv = *(const short8*)&sv[wave][t2 * 256 + d];
            #pragma unroll
            for (int e2 = 0; e2 < 8; e2++)
                acc[e2] += wt[t2] * bf2f((ushort)vv[e2]);
        }
        short8 o;
        #pragma unroll
        for (int e2 = 0; e2 < 8; e2++)
            o[e2] = (short)f2bf(acc[e2]);
        *(short8*)&qkv[base + h * 256 + d] = o;
    }
}

// -------- LayerNorm over C=2048, fp32 in place on d_out ---------------------
__global__ __launch_bounds__(256, 2)
void ln_kernel(float* __restrict__ y, const float* __restrict__ gamma,
               const float* __restrict__ beta)
{
    __shared__ float red[2][4];
    const int t = threadIdx.x;
    const size_t base = (size_t)blockIdx.x * 2048 + t * 8;
    floatx4 a = *(const floatx4*)&y[base];
    floatx4 b = *(const floatx4*)&y[base + 4];
    float f[8] = {a[0], a[1], a[2], a[3], b[0], b[1], b[2], b[3]};
    float s = 0.f, ss = 0.f;
    #pragma unroll
    for (int e = 0; e < 8; e++) { s += f[e]; ss += f[e] * f[e]; }
    #pragma unroll
    for (int off = 1; off < 64; off <<= 1) {
        s  += __shfl_xor(s, off);
        ss += __shfl_xor(ss, off);
    }
    const int wave = t >> 6, lane = t & 63;
    if (lane == 0) { red[0][wave] = s; red[1][wave] = ss; }
    __syncthreads();
    s  = red[0][0] + red[0][1] + red[0][2] + red[0][3];
    ss = red[1][0] + red[1][1] + red[1][2] + red[1][3];
    const float mu  = s * (1.f / 2048.f);
    const float var = fmaxf(ss * (1.f / 2048.f) - mu * mu, 0.f);
    const float rs  = rsqrtf(var + 1e-5f);
    floatx4 g0 = *(const floatx4*)&gamma[t * 8];
    floatx4 g1 = *(const floatx4*)&gamma[t * 8 + 4];
    floatx4 b0 = *(const floatx4*)&beta[t * 8];
    floatx4 b1 = *(const floatx4*)&beta[t * 8 + 4];
    floatx4 o0, o1;
    #pragma unroll
    for (int e = 0; e < 4; e++) {
        o0[e] = g0[e] * (f[e] - mu) * rs + b0[e];
        o1[e] = g1[e] * (f[e + 4] - mu) * rs + b1[e];
    }
    *(floatx4*)&y[base]     = o0;
    *(floatx4*)&y[base + 4] = o1;
}

extern "C" void kernel_launch(void* const* d_in, const int* in_sizes, int n_in,
                              void* d_out, int out_size, void* d_ws, size_t ws_size,
                              hipStream_t stream)
{
    const float* x     = (const float*)d_in[0];
    const float* Wq    = (const float*)d_in[1];
    const float* bq    = (const float*)d_in[2];
    const float* Wk    = (const float*)d_in[3];
    const float* bk    = (const float*)d_in[4];
    const float* Wv    = (const float*)d_in[5];
    const float* bv    = (const float*)d_in[6];
    const float* Wo    = (const float*)d_in[7];
    const float* bo    = (const float*)d_in[8];
    const float* gamma = (const float*)d_in[9];
    const float* beta  = (const float*)d_in[10];
    float* out = (float*)d_out;

    char* ws = (char*)d_ws;
    const size_t MB = 1024 * 1024;
    ushort* WqkvT = (ushort*)(ws + 0 * MB);    // 24MB: Wq^T | Wk^T | Wv^T rows
    ushort* WoT   = (ushort*)(ws + 24 * MB);   // 8MB

    const bool bigws = ws_size >= 288 * MB;
    ushort* xbf = (ushort*)(ws + 32 * MB);                      // path X: 64MB
    ushort* qkv = (ushort*)(ws + (bigws ? 96 : 32) * MB);       // 192MB fused

    dim3 tb(32, 8), tg(64, 64);
    convT2048<<<tg, tb, 0, stream>>>(Wq, WqkvT);
    convT2048<<<tg, tb, 0, stream>>>(Wk, WqkvT + 2048 * 2048);
    convT2048<<<tg, tb, 0, stream>>>(Wv, WqkvT + 2 * 2048 * 2048);
    convT2048<<<tg, tb, 0, stream>>>(Wo, WoT);

    if (bigws) {
        cvt_bf16<<<16384, 256, 0, stream>>>(x, xbf);
        // fused QKV: [16384][2048] @ [6144][2048]^T -> [16384][6144]
        gemm256<ushort, 6144><<<1536, 512, 0, stream>>>(
            xbf, 2048, WqkvT, bq, bk, bv, nullptr, qkv);
    } else {
        gemm_f32a<6144><<<6144, 256, 0, stream>>>(
            x, 2048, WqkvT, bq, bk, bv, qkv);
    }

    attn_kernel<<<4096, 256, 0, stream>>>(qkv);

    // attended lives in q-slice of fused buffer (lda=6144)
    gemm256<float, 2048><<<512, 512, 0, stream>>>(
        qkv, 6144, WoT, bo, bo, bo, x, out);

    ln_kernel<<<16384, 256, 0, stream>>>(out, gamma, beta);
}